// Round 8
// baseline (110.821 us; speedup 1.0000x reference)
//
#include <hip/hip_runtime.h>
#include <math.h>

#define NN 50000
#define NE 800000
#define FIN 128
#define NC 10
#define NEG 0.2f

#define NB 196        // coarse buckets = ceil(NN/256), bucket = dst>>8
#define CHUNK 4096    // edges per pass1 block
#define P1B ((NE + CHUNK - 1) / CHUNK)   // 196
#define CAP 5120      // temp capacity per bucket
#define G1T ((NN + 127) / 128)           // 391 gemm1 tiles

typedef unsigned int uint;
typedef unsigned char uchar;
typedef _Float16 h2 __attribute__((ext_vector_type(2)));
typedef __fp16 hb2 __attribute__((ext_vector_type(2)));
union U2H { uint u; h2 h; };

// pack 2 floats -> half2 bits (builtin returns __fp16v2; go through a union)
__device__ __forceinline__ uint pkrtz_u(float a, float b) {
    union { hb2 f; uint u; } r;
    r.f = __builtin_amdgcn_cvt_pkrtz(a, b);
    return r.u;
}

__device__ __forceinline__ float dot2f(h2 a, h2 b, float c) {
#if __has_builtin(__builtin_amdgcn_fdot2)
    return __builtin_amdgcn_fdot2(a, b, c, false);
#else
    return fmaf((float)a.x, (float)b.x, fmaf((float)a.y, (float)b.y, c));
#endif
}

// packed leaky-relu: max(v, 0.2*v)
__device__ __forceinline__ h2 lrelu2(h2 v) {
    return __builtin_elementwise_max(v, v * (_Float16)0.2f);
}

template<int CTRL>
__device__ __forceinline__ float dpp_add(float x) {
    int y = __builtin_amdgcn_update_dpp(0, __float_as_int(x), CTRL, 0xF, 0xF, true);
    return x + __int_as_float(y);
}
// sum over aligned 8-lane groups (= one attention head's channels in half2 layout)
__device__ __forceinline__ float red8(float t) {
    t = dpp_add<0xB1>(t);
    t = dpp_add<0x4E>(t);
    t = dpp_add<0x141>(t);
    return t;
}

__device__ __forceinline__ int excl_scan256(int v, int* sc) {
    const int t = threadIdx.x;
    sc[t] = v;
    __syncthreads();
    for (int o = 1; o < 256; o <<= 1) {
        int u = (t >= o) ? sc[t - o] : 0;
        __syncthreads();
        sc[t] += u;
        __syncthreads();
    }
    return sc[t] - v;
}

// ---------------- tiny init ----------------

__global__ void k_zinit(int* __restrict__ g) {
    if (threadIdx.x < NB) g[threadIdx.x] = 0;
}

// ---------------- fused kernel A: pass1 bucket-scatter || gemm1(f16) ----------------

__device__ void pass1_body(const int* __restrict__ ei, uint* __restrict__ temp,
                           int* __restrict__ gcursor, char* smraw) {
    uint*  pk = (uint*)smraw;                 // 16384 B [4096]
    uchar* bk = (uchar*)(smraw + 16384);      // 4096 B
    int* h  = (int*)(smraw + 20480);          // 1024
    int* h2_ = (int*)(smraw + 21504);         // 1024
    int* gb = (int*)(smraw + 22528);          // 1024
    int* lb = (int*)(smraw + 23552);          // 1024
    int* sc = (int*)(smraw + 24576);          // 1024
    const int t = threadIdx.x;
    const int e0 = blockIdx.x * CHUNK;
    const int cnt = min(CHUNK, NE - e0);

    h[t] = 0; h2_[t] = 0;
    __syncthreads();
    for (int i = t; i < cnt; i += 256) {
        int d = ei[NE + e0 + i];
        atomicAdd(&h[d >> 8], 1);
    }
    __syncthreads();
    const int hv = h[t];
    const int ex = excl_scan256(hv, sc);
    lb[t] = ex;
    if (t < NB && hv > 0) gb[t] = atomicAdd(&gcursor[t], hv);
    __syncthreads();
    for (int i = t; i < cnt; i += 256) {
        int s = ei[e0 + i];
        int d = ei[NE + e0 + i];
        int b = d >> 8;
        int r = atomicAdd(&h2_[b], 1);
        int pos = lb[b] + r;
        pk[pos] = ((uint)s << 8) | ((uint)d & 255u);
        bk[pos] = (uchar)b;
    }
    __syncthreads();
    for (int i = t; i < cnt; i += 256) {
        uint v = pk[i];
        int b = bk[i];
        int pos = gb[b] + (i - lb[b]);
        if (pos < CAP) temp[b * CAP + pos] = v;
    }
}

// xl/xr stored as half2 pairs: oh2[n*32 + pair]
__device__ void gemm1_body(const float* __restrict__ x, const float* __restrict__ W,
                           uint* __restrict__ oh2, int n0, char* smraw) {
    uint (*Wsh)[64]  = (uint(*)[64])smraw;             // [64 kp][64 col] 16KB
    uint (*xTh)[128] = (uint(*)[128])(smraw + 16384);  // [16 kp][128 node] 8KB
    const int t = threadIdx.x;

    for (int i = t; i < 4096; i += 256) {   // stage W as k-paired half2
        int kp = i >> 6, col = i & 63;
        Wsh[kp][col] = pkrtz_u(W[(2 * kp) * 64 + col], W[(2 * kp + 1) * 64 + col]);
    }

    const int tn = t >> 4;          // node group: nodes tn*8..+7
    const int tc = t & 15;          // col group : cols tc*4..+3
    float acc[8][4] = {};
    const int sn = t >> 1;          // staging node 0..127
    const int kp0 = (t & 1) * 8;    // staging k-pair offset within chunk

    for (int kc = 0; kc < FIN; kc += 32) {
        __syncthreads();
        {
            int gn = n0 + sn;
            float4 v0, v1, v2, v3;
            if (gn < NN) {
                const float4* xr_ = (const float4*)(x + (size_t)gn * FIN + kc + kp0 * 2);
                v0 = xr_[0]; v1 = xr_[1]; v2 = xr_[2]; v3 = xr_[3];
            } else {
                v0 = v1 = v2 = v3 = make_float4(0.f, 0.f, 0.f, 0.f);
            }
            xTh[kp0 + 0][sn] = pkrtz_u(v0.x, v0.y);
            xTh[kp0 + 1][sn] = pkrtz_u(v0.z, v0.w);
            xTh[kp0 + 2][sn] = pkrtz_u(v1.x, v1.y);
            xTh[kp0 + 3][sn] = pkrtz_u(v1.z, v1.w);
            xTh[kp0 + 4][sn] = pkrtz_u(v2.x, v2.y);
            xTh[kp0 + 5][sn] = pkrtz_u(v2.z, v2.w);
            xTh[kp0 + 6][sn] = pkrtz_u(v3.x, v3.y);
            xTh[kp0 + 7][sn] = pkrtz_u(v3.z, v3.w);
        }
        __syncthreads();
        const int kpc = kc >> 1;
#pragma unroll
        for (int kp = 0; kp < 16; ++kp) {
            uint4 wv = *(const uint4*)&Wsh[kpc + kp][tc * 4];
            uint4 xa = *(const uint4*)&xTh[kp][tn * 8];
            uint4 xb = *(const uint4*)&xTh[kp][tn * 8 + 4];
            U2H w0, w1, w2, w3, x0, x1, x2, x3, x4, x5, x6, x7;
            w0.u = wv.x; w1.u = wv.y; w2.u = wv.z; w3.u = wv.w;
            x0.u = xa.x; x1.u = xa.y; x2.u = xa.z; x3.u = xa.w;
            x4.u = xb.x; x5.u = xb.y; x6.u = xb.z; x7.u = xb.w;
            h2 xs[8] = {x0.h, x1.h, x2.h, x3.h, x4.h, x5.h, x6.h, x7.h};
#pragma unroll
            for (int i = 0; i < 8; ++i) {
                acc[i][0] = dot2f(xs[i], w0.h, acc[i][0]);
                acc[i][1] = dot2f(xs[i], w1.h, acc[i][1]);
                acc[i][2] = dot2f(xs[i], w2.h, acc[i][2]);
                acc[i][3] = dot2f(xs[i], w3.h, acc[i][3]);
            }
        }
    }
#pragma unroll
    for (int i = 0; i < 8; ++i) {
        int n = n0 + tn * 8 + i;
        if (n < NN) {
            uint p0 = pkrtz_u(acc[i][0], acc[i][1]);
            uint p1 = pkrtz_u(acc[i][2], acc[i][3]);
            *(uint2*)&oh2[(size_t)n * 32 + tc * 2] = make_uint2(p0, p1);
        }
    }
}

__global__ __launch_bounds__(256) void k_fusedA(const float* __restrict__ x,
                                                const int* __restrict__ ei,
                                                const float* __restrict__ W1l,
                                                const float* __restrict__ W1r,
                                                uint* __restrict__ xlh2,
                                                uint* __restrict__ xrh2,
                                                uint* __restrict__ temp,
                                                int* __restrict__ gcursor) {
    __shared__ __align__(16) char smraw[25600];
    if (blockIdx.x < P1B) {
        pass1_body(ei, temp, gcursor, smraw);
    } else {
        int g = blockIdx.x - P1B;
        bool left = g < G1T;
        int n0 = (left ? g : g - G1T) * 128;
        gemm1_body(x, left ? W1l : W1r, left ? xlh2 : xrh2, n0, smraw);
    }
}

// ---------------- pass2: per-bucket exact CSR ----------------

__global__ __launch_bounds__(256) void k_pass2(const uint* __restrict__ temp,
                                               const int* __restrict__ gcursor,
                                               int* __restrict__ rowptr,
                                               int* __restrict__ deg,
                                               int* __restrict__ csr_src) {
    __shared__ uint P[CAP];
    __shared__ int nh[256], nbx[256], ncur[256], sc[256];
    __shared__ int csrbase_s;
    const int t = threadIdx.x;
    const int b = blockIdx.x;

    int gc = (t < NB) ? gcursor[t] : 0;
    int base_ex = excl_scan256(gc, sc);
    if (t == b) csrbase_s = base_ex;
    nh[t] = 0; ncur[t] = 0;
    __syncthreads();
    const int csrbase = csrbase_s;
    const int cnt = min(gcursor[b], CAP);

    for (int i = t; i < cnt; i += 256) {
        uint v = temp[b * CAP + i];
        P[i] = v;
        atomicAdd(&nh[v & 255u], 1);
    }
    __syncthreads();
    const int c = nh[t];
    const int nb_ex = excl_scan256(c, sc);
    nbx[t] = nb_ex;
    const int gnode = b * 256 + t;
    if (gnode < NN) { rowptr[gnode] = csrbase + nb_ex; deg[gnode] = c; }
    __syncthreads();
    for (int i = t; i < cnt; i += 256) {
        uint v = P[i];
        int l = (int)(v & 255u);
        int r = atomicAdd(&ncur[l], 1);
        csr_src[csrbase + nbx[l] + r] = (int)(v >> 8);
    }
}

// ---------------- layer 1 aggregate: masked batch of 8 edges in flight ----------------

__global__ __launch_bounds__(256) void k_agg1(const uint* __restrict__ xlh2,
                                              const uint* __restrict__ xrh2,
                                              const int* __restrict__ rowptr,
                                              const int* __restrict__ deg,
                                              const int* __restrict__ csr_src,
                                              const float* __restrict__ att1,
                                              const float* __restrict__ b1,
                                              uint* __restrict__ hbh2) {
    const int node = blockIdx.x * 4 + (threadIdx.x >> 6);
    if (node >= NN) return;
    const int lane = threadIdx.x & 63;
    const int fl = lane & 31;        // feature-pair
    const int hid = lane >> 5;       // edge-half id
    float2 av = *(const float2*)&att1[2 * fl];
    U2H att; att.u = pkrtz_u(av.x, av.y);
    U2H xrf; xrf.u = xrh2[(size_t)node * 32 + fl];
    const int start = rowptr[node];
    const int dg = deg[node];
    const int permbase = (lane & 32) >> 3;   // 0 or 4

    float denom = 0.f, acc0 = 0.f, acc1 = 0.f;
    for (int base = 0; base < dg; base += 64) {
        int idx = base + lane;
        int srcs = (idx < dg) ? csr_src[start + idx] : 0;
        int rem = dg - base; if (rem > 64) rem = 64;
        int iters = (rem + 1) >> 1;
        int thr = (rem - hid + 1) >> 1;      // edge (2j+hid) valid iff j < thr
        // masked batches of 8: all gathers independent -> 8-deep MLP
        for (int jj = 0; jj < iters; jj += 8) {
            int s[8]; U2H v[8];
#pragma unroll
            for (int k = 0; k < 8; ++k)
                s[k] = __builtin_amdgcn_ds_bpermute((jj + k) * 8 + permbase, srcs);
#pragma unroll
            for (int k = 0; k < 8; ++k)
                v[k].u = xlh2[(size_t)s[k] * 32 + fl];
#pragma unroll
            for (int k = 0; k < 8; ++k) {
                float tl = red8(dot2f(lrelu2(v[k].h + xrf.h), att.h, 0.f));
                float e = (jj + k < thr) ? __expf(tl) : 0.f;
                denom += e;
                acc0 = fmaf(e, (float)v[k].h.x, acc0);
                acc1 = fmaf(e, (float)v[k].h.y, acc1);
            }
        }
    }
    denom += __shfl_xor(denom, 32);
    acc0  += __shfl_xor(acc0, 32);
    acc1  += __shfl_xor(acc1, 32);
    if (lane < 32) {
        float r = (dg > 0) ? (1.0f / denom) : 0.f;
        float2 bv = *(const float2*)&b1[2 * fl];
        float o0 = fmaf(acc0, r, bv.x);
        float o1 = fmaf(acc1, r, bv.y);
        o0 = o0 > 0.f ? o0 : expm1f(o0);
        o1 = o1 > 0.f ? o1 : expm1f(o1);
        hbh2[(size_t)node * 32 + fl] = pkrtz_u(o0, o1);
    }
}

// ---------------- layer 2 GEMM: node per thread, packed half2 outputs ----------------

__global__ __launch_bounds__(256) void k_gemm2(const uint* __restrict__ hbh2,
                                               const float* __restrict__ W2l,
                                               const float* __restrict__ W2r,
                                               uint* __restrict__ xl2h,
                                               uint* __restrict__ xr2h) {
    int n = blockIdx.x * 256 + threadIdx.x;
    if (n >= NN) return;
    float al[NC] = {}, ar[NC] = {};
    const uint4* hr4 = (const uint4*)(hbh2 + (size_t)n * 32);
#pragma unroll
    for (int q = 0; q < 8; ++q) {
        uint4 qq = hr4[q];
        uint uu[4] = {qq.x, qq.y, qq.z, qq.w};
#pragma unroll
        for (int j = 0; j < 4; ++j) {
            U2H hh; hh.u = uu[j];
            float f0 = (float)hh.h.x, f1 = (float)hh.h.y;
            int k = q * 8 + j * 2;
            const float* wl0 = W2l + k * NC;
            const float* wr0 = W2r + k * NC;
#pragma unroll
            for (int c = 0; c < NC; ++c) {
                al[c] = fmaf(f0, wl0[c], fmaf(f1, wl0[NC + c], al[c]));
                ar[c] = fmaf(f0, wr0[c], fmaf(f1, wr0[NC + c], ar[c]));
            }
        }
    }
    uint p0 = pkrtz_u(al[0], al[1]);
    uint p1 = pkrtz_u(al[2], al[3]);
    uint p2 = pkrtz_u(al[4], al[5]);
    uint p3 = pkrtz_u(al[6], al[7]);
    uint p4 = pkrtz_u(al[8], al[9]);
    *(uint4*)&xl2h[(size_t)n * 8]     = make_uint4(p0, p1, p2, p3);
    *(uint4*)&xl2h[(size_t)n * 8 + 4] = make_uint4(p4, 0u, 0u, 0u);
    p0 = pkrtz_u(ar[0], ar[1]);
    p1 = pkrtz_u(ar[2], ar[3]);
    p2 = pkrtz_u(ar[4], ar[5]);
    p3 = pkrtz_u(ar[6], ar[7]);
    p4 = pkrtz_u(ar[8], ar[9]);
    *(uint4*)&xr2h[(size_t)n * 8]     = make_uint4(p0, p1, p2, p3);
    *(uint4*)&xr2h[(size_t)n * 8 + 4] = make_uint4(p4, 0u, 0u, 0u);
}

// ---------------- layer 2 aggregate: masked batch of 4 (32 edges/wave in flight) ----------------

__global__ __launch_bounds__(256) void k_agg2(const uint* __restrict__ xl2h,
                                              const uint* __restrict__ xr2h,
                                              const int* __restrict__ rowptr,
                                              const int* __restrict__ deg,
                                              const int* __restrict__ csr_src,
                                              const float* __restrict__ att2,
                                              const float* __restrict__ b2,
                                              float* __restrict__ out) {
    const int node = blockIdx.x * 4 + (threadIdx.x >> 6);
    if (node >= NN) return;
    const int lane = threadIdx.x & 63;
    const int fp = lane & 7;         // feature-pair (0..4 real, 5..7 pad)
    const int eg = lane >> 3;        // edge group 0..7
    U2H att;
    if (fp < 5) {
        float2 av = *(const float2*)&att2[2 * fp];
        att.u = pkrtz_u(av.x, av.y);
    } else {
        att.u = 0;
    }
    U2H xrf; xrf.u = xr2h[(size_t)node * 8 + fp];
    const int start = rowptr[node];
    const int dg = deg[node];
    const int permbase = eg * 4;

    float denom = 0.f, acc0 = 0.f, acc1 = 0.f;
    for (int base = 0; base < dg; base += 64) {
        int idx = base + lane;
        int srcs = (idx < dg) ? csr_src[start + idx] : 0;
        int rem = dg - base; if (rem > 64) rem = 64;
        int iters = (rem + 7) >> 3;
        int thr = (rem - eg + 7) >> 3;       // edge (8j+eg) valid iff j < thr
        for (int jj = 0; jj < iters; jj += 4) {
            int s[4]; U2H v[4];
#pragma unroll
            for (int k = 0; k < 4; ++k)
                s[k] = __builtin_amdgcn_ds_bpermute((jj + k) * 32 + permbase, srcs);
#pragma unroll
            for (int k = 0; k < 4; ++k)
                v[k].u = xl2h[(size_t)s[k] * 8 + fp];
#pragma unroll
            for (int k = 0; k < 4; ++k) {
                float tl = red8(dot2f(lrelu2(v[k].h + xrf.h), att.h, 0.f));
                float e = (jj + k < thr) ? __expf(tl) : 0.f;
                denom += e;
                acc0 = fmaf(e, (float)v[k].h.x, acc0);
                acc1 = fmaf(e, (float)v[k].h.y, acc1);
            }
        }
    }
#pragma unroll
    for (int m = 8; m <= 32; m <<= 1) {
        denom += __shfl_xor(denom, m);
        acc0  += __shfl_xor(acc0, m);
        acc1  += __shfl_xor(acc1, m);
    }
    if (lane < 5) {   // eg==0, fp<5
        float r = (dg > 0) ? (1.0f / denom) : 0.f;
        float2 o;
        o.x = fmaf(acc0, r, b2[2 * fp]);
        o.y = fmaf(acc1, r, b2[2 * fp + 1]);
        *(float2*)&out[(size_t)node * NC + 2 * fp] = o;
    }
}

// ---------------- launch ----------------

extern "C" void kernel_launch(void* const* d_in, const int* in_sizes, int n_in,
                              void* d_out, int out_size, void* d_ws, size_t ws_size,
                              hipStream_t stream) {
    const float* x    = (const float*)d_in[0];
    const int*   ei   = (const int*)d_in[1];
    const float* W1l  = (const float*)d_in[2];
    const float* W1r  = (const float*)d_in[3];
    const float* att1 = (const float*)d_in[4];
    const float* b1   = (const float*)d_in[5];
    const float* W2l  = (const float*)d_in[6];
    const float* W2r  = (const float*)d_in[7];
    const float* att2 = (const float*)d_in[8];
    const float* b2   = (const float*)d_in[9];
    float* out = (float*)d_out;

    char* w = (char*)d_ws;
    size_t off = 0;
    auto alloc = [&](size_t bytes) -> void* {
        void* p = w + off;
        off = (off + bytes + 255) & ~(size_t)255;
        return p;
    };
    uint* xlh2   = (uint*)alloc((size_t)NN * 32 * 4);
    uint* xrh2   = (uint*)alloc((size_t)NN * 32 * 4);
    uint* hbh2   = (uint*)alloc((size_t)NN * 32 * 4);
    uint* xl2h   = (uint*)alloc((size_t)NN * 8 * 4);
    uint* xr2h   = (uint*)alloc((size_t)NN * 8 * 4);
    uint* temp   = (uint*)alloc((size_t)NB * CAP * 4);
    int*  gcursor = (int*)alloc((size_t)NB * 4);
    int*  rowptr  = (int*)alloc((size_t)NN * 4);
    int*  deg     = (int*)alloc((size_t)NN * 4);
    int*  csr_src = (int*)alloc((size_t)NE * 4);

    k_zinit<<<1, 256, 0, stream>>>(gcursor);
    k_fusedA<<<P1B + 2 * G1T, 256, 0, stream>>>(x, ei, W1l, W1r, xlh2, xrh2, temp, gcursor);
    k_pass2<<<NB, 256, 0, stream>>>(temp, gcursor, rowptr, deg, csr_src);
    k_agg1<<<(NN + 3) / 4, 256, 0, stream>>>(xlh2, xrh2, rowptr, deg, csr_src, att1, b1, hbh2);
    k_gemm2<<<(NN + 255) / 256, 256, 0, stream>>>(hbh2, W2l, W2r, xl2h, xr2h);
    k_agg2<<<(NN + 3) / 4, 256, 0, stream>>>(xl2h, xr2h, rowptr, deg, csr_src, att2, b2, out);
}